// Round 2
// baseline (2023.718 us; speedup 1.0000x reference)
//
#include <hip/hip_runtime.h>
#include <hip/hip_fp16.h>

// LaplacianKnn:  y'[i] = a*y[i] + b * sum_j m_e * y[nbr_e],  out = dot(x, y_nu)
//   m_e = t_e/s_i, t_e = exp(-dist_e/eps)*Dinv[nbr_e], s_i = row-sum(t)
//   a = 4/eps + 2nu/k^2 + 10,  b = -4/eps
// R6: gathers are L2-hit and request-limited, ~237us/pass (0.22 req/cyc/CU).
// R7: sc0 L1-bypass = exact null -> hard request-rate wall, not cache policy.
// R8: cut a pass algebraically: x^T L^3 x = (L^T x) . (L^2 x).
//   u = L^T x = a*x + b*S, S[j] = sum_e m_e*x[i]  -- a SCATTER, fused into
//   fsweep (m_e, x[i] already in registers; fire-and-forget atomic_add_f32).
//   Final pass computes y2 = L*y1 and dots with u on the fly.
//   Passes: dinv(stream) + fsweep(gather+scatter) + dot-sweep(gather). 3 random
//   ops total (the algorithmic floor), 3 kernels instead of 4.

typedef float __attribute__((ext_vector_type(4))) floatx4;
typedef unsigned int uint32;

static constexpr int BLOCK = 256;

// fire-and-forget f32 atomic add: guarantee global_atomic_add_f32 (no CAS loop,
// no return value -> no latency occupancy on the wave).
__device__ __forceinline__ void atomic_add_f32_nr(float* p, float v) {
  asm volatile("global_atomic_add_f32 %0, %1, off" :: "v"(p), "v"(v) : "memory");
}

// ---- pass 1 (coalesced only): z4[i] = half2(1/sum_j exp(-d/eps), x[i]) ----
__global__ __launch_bounds__(256) void dinv_kernel(
    const float* __restrict__ dist, const float* __restrict__ x,
    const float* __restrict__ eps_p,
    __half2* __restrict__ z4, int n_edges) {
  int t = blockIdx.x * BLOCK + threadIdx.x;
  int e4 = t << 2;
  if (e4 >= n_edges) return;
  float inv_eps = 1.0f / eps_p[0];
  floatx4 d = __builtin_nontemporal_load((const floatx4*)(dist + e4));
  float s = __expf(-d.x * inv_eps) + __expf(-d.y * inv_eps) +
            __expf(-d.z * inv_eps) + __expf(-d.w * inv_eps);
  #pragma unroll
  for (int off = 4; off > 0; off >>= 1) s += __shfl_down(s, off, 8);
  if ((t & 7) == 0) {
    int node = t >> 3;
    z4[node] = __halves2half2(__float2half(1.0f / s), __float2half(x[node]));
  }
}

// ---- pass 2: fused pack + sweep1 (y1 = L x) + scatter (S[j] += m_e*x[i]) ----
__global__ __launch_bounds__(256) void fsweep_kernel(
    const float* __restrict__ dist, const int* __restrict__ nbr,
    const __half2* __restrict__ z4,
    const float* __restrict__ x, const float* __restrict__ eps_p,
    const float* __restrict__ k_p, const int* __restrict__ nu_p,
    uint32* __restrict__ pk, float* __restrict__ yout,
    float* __restrict__ S, int n_edges) {
  int e = blockIdx.x * BLOCK + threadIdx.x;
  if (e >= n_edges) return;
  float inv_eps = 1.0f / eps_p[0];
  int j = __builtin_nontemporal_load(nbr + e);
  float d = __builtin_nontemporal_load(dist + e);
  __half2 z = z4[j];                       // PLAIN gather, L2-resident 4MB
  float t = __expf(-d * inv_eps) * __low2float(z);   // t_e = exp * Dinv[j]
  float g = t * __high2float(z);                     // t_e * x[j]
  float s = t;
  #pragma unroll
  for (int off = 1; off < 32; off <<= 1) s += __shfl_xor(s, off, 32);  // row sum
  float inv_s = 1.0f / s;
  // scatter for u = L^T x: S[j] += m_e * x[i]  (fire-and-forget)
  float xi = x[e >> 5];                    // per-row constant, broadcast read
  atomic_add_f32_nr(S + j, t * inv_s * xi);
  // emit packed edge for the final sweep
  uint32 mq = (uint32)__float2uint_rn(t * 4096.0f * inv_s);
  if (mq > 4095u) mq = 4095u;
  __builtin_nontemporal_store(((uint32)j << 12) | mq, pk + e);
  // y1[i] = a*x[i] + b*g/s  (leader)
  #pragma unroll
  for (int off = 16; off > 0; off >>= 1) g += __shfl_down(g, off, 32);
  if ((threadIdx.x & 31) == 0) {
    int node = e >> 5;
    float kk = k_p[0];
    float a = 4.0f * inv_eps + 2.0f * (float)nu_p[0] / (kk * kk) + 10.0f;
    float b = -4.0f * inv_eps;
    yout[node] = a * x[node] + b * g * inv_s;   // PLAIN store: keep y1 hot in L2
  }
}

// ---- pass 3: y2 = L y1 fused with out = sum u[i]*y2[i], u = a*x + b*S ----
__global__ __launch_bounds__(256) void dot_kernel(
    const uint32* __restrict__ pk,
    const float* __restrict__ y1, const float* __restrict__ x,
    const float* __restrict__ S,
    const float* __restrict__ eps_p, const float* __restrict__ k_p,
    const int* __restrict__ nu_p,
    float* __restrict__ out, int n_edges) {
  __shared__ float bsum;
  if (threadIdx.x == 0) bsum = 0.0f;
  __syncthreads();
  float inv_eps = 1.0f / eps_p[0];
  float kk = k_p[0];
  float a  = 4.0f * inv_eps + 2.0f * (float)nu_p[0] / (kk * kk) + 10.0f;
  float b  = -4.0f * inv_eps;
  float bq = b * (1.0f / 4096.0f);
  int stride = gridDim.x * BLOCK;
  for (int e = blockIdx.x * BLOCK + threadIdx.x; e < n_edges; e += stride) {
    uint32 p = __builtin_nontemporal_load(pk + e);   // single 4B stream load/edge
    float g = (float)(p & 0xFFFu) * y1[p >> 12];     // PLAIN gather, L2-resident
    #pragma unroll
    for (int off = 16; off > 0; off >>= 1) g += __shfl_down(g, off, 32);
    if ((threadIdx.x & 31) == 0) {
      int node = e >> 5;
      float y2 = a * y1[node] + bq * g;              // (L^2 x)[node]
      float u  = a * x[node] + b * S[node];          // (L^T x)[node]
      atomicAdd(&bsum, u * y2);
    }
  }
  __syncthreads();
  if (threadIdx.x == 0) atomicAdd(out, bsum);
}

extern "C" void kernel_launch(void* const* d_in, const int* in_sizes, int n_in,
                              void* d_out, int out_size, void* d_ws, size_t ws_size,
                              hipStream_t stream) {
  const float* x     = (const float*)d_in[0];
  const int*   nbr   = (const int*)d_in[1];
  const float* dist  = (const float*)d_in[2];
  const float* eps_p = (const float*)d_in[3];
  const float* k_p   = (const float*)d_in[4];
  const int*   nu_p  = (const int*)d_in[5];
  float* out = (float*)d_out;

  int n  = in_sizes[0];   // 1,000,000 nodes  (< 2^20 -> 20-bit index fits)
  int ne = in_sizes[1];   // 32,000,000 edges

  uint32* pk   = (uint32*)d_ws;         // [ne]  packed edges
  __half2* z4  = (__half2*)(pk + ne);   // [n]   (Dinv, x) in f16
  float* y1    = (float*)(z4 + n);      // [n]
  float* S     = y1 + n;                // [n]   scatter accum for u = L^T x

  (void)hipMemsetAsync(d_out, 0, sizeof(float), stream);
  (void)hipMemsetAsync(S, 0, (size_t)n * sizeof(float), stream);

  int gridE = (ne + BLOCK - 1) / BLOCK;            // 1 edge/thread
  int grid4 = (ne + BLOCK * 4 - 1) / (BLOCK * 4);  // 4 edges/thread
  dinv_kernel<<<grid4, BLOCK, 0, stream>>>(dist, x, eps_p, z4, ne);
  fsweep_kernel<<<gridE, BLOCK, 0, stream>>>(dist, nbr, z4, x, eps_p, k_p, nu_p, pk, y1, S, ne);
  dot_kernel<<<gridE / 8, BLOCK, 0, stream>>>(pk, y1, x, S, eps_p, k_p, nu_p, out, ne);
}

// Round 3
// 1569.335 us; speedup vs baseline: 1.2895x; 1.2895x over previous
//
#include <hip/hip_runtime.h>
#include <hip/hip_fp16.h>
#include <hip/hip_cooperative_groups.h>

namespace cg = cooperative_groups;

// LaplacianKnn:  y'[i] = a*y[i] + b * sum_j m_e * y[nbr_e],  out = dot(x, y_nu)
//   m_e = t_e/s_i, t_e = exp(-dist_e/eps)*Dinv[nbr_e], s_i = row-sum(t)
// R6: gathers are L2-hit, request-limited ~237us/pass (0.22 lane-req/cy/CU).
// R7: sc0 L1-bypass null -> not cache policy. sweep<true> at 1/8 grid also
//     237us -> not ILP/occupancy. Hard TCP divergent-request wall.
// R8: scatter u=L^T x via atomics = 6.5x WORSE (atomics resolve memory-side
//     past the non-coherent XCD L2s; 1.6GB HBM traffic). Scatters dead.
// R9: floor = 3 gather passes (711us) + dinv (~25us). Baseline 891 has
//     ~140us of inter-dispatch drain/tail (4x 125K-block launches). Fuse all
//     passes into ONE cooperative kernel, persistent blocks, grid.sync()
//     between phases. Fallback to 4-kernel path if coop launch fails.

typedef float __attribute__((ext_vector_type(4))) floatx4;
typedef unsigned int uint32;

static constexpr int BLOCK = 256;

// ============================ mega kernel ============================
__global__ __launch_bounds__(256, 8) void mega_kernel(
    const float* __restrict__ x, const int* __restrict__ nbr,
    const float* __restrict__ dist,
    const float* __restrict__ eps_p, const float* __restrict__ k_p,
    const int* __restrict__ nu_p,
    uint32* __restrict__ pk, __half2* __restrict__ z4,
    float* __restrict__ y1, float* __restrict__ y2,
    float* __restrict__ out, int n_edges) {
  cg::grid_group grid = cg::this_grid();
  __shared__ float bsum;
  const int tid = blockIdx.x * BLOCK + threadIdx.x;
  const int nth = gridDim.x * BLOCK;
  const float inv_eps = 1.0f / eps_p[0];
  const float kk = k_p[0];
  const float a = 4.0f * inv_eps + 2.0f * (float)nu_p[0] / (kk * kk) + 10.0f;
  const float b = -4.0f * inv_eps;
  const float bq = b * (1.0f / 4096.0f);

  if (tid == 0) *out = 0.0f;

  // ---- P0: z4[i] = half2(1/rowsum exp(-d/eps), x[i]); 4 edges/thread ----
  const int nq = n_edges >> 2;
  for (int t = tid; t < nq; t += nth) {
    floatx4 d = __builtin_nontemporal_load((const floatx4*)(dist + (t << 2)));
    float s = __expf(-d.x * inv_eps) + __expf(-d.y * inv_eps) +
              __expf(-d.z * inv_eps) + __expf(-d.w * inv_eps);
    #pragma unroll
    for (int off = 4; off > 0; off >>= 1) s += __shfl_down(s, off, 8);
    if ((t & 7) == 0) {
      int node = t >> 3;
      z4[node] = __halves2half2(__float2half(1.0f / s), __float2half(x[node]));
    }
  }
  grid.sync();

  // ---- P1: fused pack + y1 = L x (one 4B gather/edge from 4MB z4) ----
  for (int e = tid; e < n_edges; e += nth) {
    int j = __builtin_nontemporal_load(nbr + e);
    float d = __builtin_nontemporal_load(dist + e);
    __half2 z = z4[j];                               // gather, L2-resident
    float t = __expf(-d * inv_eps) * __low2float(z); // t_e = exp * Dinv[j]
    float g = t * __high2float(z);                   // t_e * x[j]
    float s = t;
    #pragma unroll
    for (int off = 1; off < 32; off <<= 1) s += __shfl_xor(s, off, 32);
    float inv_s = 1.0f / s;
    uint32 mq = (uint32)__float2uint_rn(t * 4096.0f * inv_s);
    if (mq > 4095u) mq = 4095u;
    __builtin_nontemporal_store(((uint32)j << 12) | mq, pk + e);
    #pragma unroll
    for (int off = 16; off > 0; off >>= 1) g += __shfl_down(g, off, 32);
    if ((threadIdx.x & 31) == 0) {
      int node = e >> 5;
      y1[node] = a * x[node] + b * g * inv_s;        // plain store: keep hot
    }
  }
  grid.sync();

  // ---- P2: y2 = L y1 ----
  for (int e = tid; e < n_edges; e += nth) {
    uint32 p = __builtin_nontemporal_load(pk + e);
    float g = (float)(p & 0xFFFu) * y1[p >> 12];     // gather, L2-resident
    #pragma unroll
    for (int off = 16; off > 0; off >>= 1) g += __shfl_down(g, off, 32);
    if ((threadIdx.x & 31) == 0) {
      int node = e >> 5;
      y2[node] = a * y1[node] + bq * g;
    }
  }
  grid.sync();

  // ---- P3: out = sum x[i] * (L y2)[i] ----
  if (threadIdx.x == 0) bsum = 0.0f;
  __syncthreads();
  float acc = 0.0f;
  for (int e = tid; e < n_edges; e += nth) {
    uint32 p = __builtin_nontemporal_load(pk + e);
    float g = (float)(p & 0xFFFu) * y2[p >> 12];     // gather, L2-resident
    #pragma unroll
    for (int off = 16; off > 0; off >>= 1) g += __shfl_down(g, off, 32);
    if ((threadIdx.x & 31) == 0) {
      int node = e >> 5;
      acc += x[node] * (a * y2[node] + bq * g);
    }
  }
  if ((threadIdx.x & 31) == 0) atomicAdd(&bsum, acc);
  __syncthreads();
  if (threadIdx.x == 0) atomicAdd(out, bsum);
}

// ===================== fallback: proven 4-kernel path =====================
__global__ __launch_bounds__(256) void dinv_kernel(
    const float* __restrict__ dist, const float* __restrict__ x,
    const float* __restrict__ eps_p,
    __half2* __restrict__ z4, int n_edges) {
  int t = blockIdx.x * BLOCK + threadIdx.x;
  int e4 = t << 2;
  if (e4 >= n_edges) return;
  float inv_eps = 1.0f / eps_p[0];
  floatx4 d = __builtin_nontemporal_load((const floatx4*)(dist + e4));
  float s = __expf(-d.x * inv_eps) + __expf(-d.y * inv_eps) +
            __expf(-d.z * inv_eps) + __expf(-d.w * inv_eps);
  #pragma unroll
  for (int off = 4; off > 0; off >>= 1) s += __shfl_down(s, off, 8);
  if ((t & 7) == 0) {
    int node = t >> 3;
    z4[node] = __halves2half2(__float2half(1.0f / s), __float2half(x[node]));
  }
}

__global__ __launch_bounds__(256) void fsweep_kernel(
    const float* __restrict__ dist, const int* __restrict__ nbr,
    const __half2* __restrict__ z4,
    const float* __restrict__ x, const float* __restrict__ eps_p,
    const float* __restrict__ k_p, const int* __restrict__ nu_p,
    uint32* __restrict__ pk, float* __restrict__ yout, int n_edges) {
  int e = blockIdx.x * BLOCK + threadIdx.x;
  if (e >= n_edges) return;
  float inv_eps = 1.0f / eps_p[0];
  int j = __builtin_nontemporal_load(nbr + e);
  float d = __builtin_nontemporal_load(dist + e);
  __half2 z = z4[j];
  float t = __expf(-d * inv_eps) * __low2float(z);
  float g = t * __high2float(z);
  float s = t;
  #pragma unroll
  for (int off = 1; off < 32; off <<= 1) s += __shfl_xor(s, off, 32);
  float inv_s = 1.0f / s;
  uint32 mq = (uint32)__float2uint_rn(t * 4096.0f * inv_s);
  if (mq > 4095u) mq = 4095u;
  __builtin_nontemporal_store(((uint32)j << 12) | mq, pk + e);
  #pragma unroll
  for (int off = 16; off > 0; off >>= 1) g += __shfl_down(g, off, 32);
  if ((threadIdx.x & 31) == 0) {
    int node = e >> 5;
    float kk = k_p[0];
    float a = 4.0f * inv_eps + 2.0f * (float)nu_p[0] / (kk * kk) + 10.0f;
    float b = -4.0f * inv_eps;
    yout[node] = a * x[node] + b * g * inv_s;
  }
}

template <bool LAST>
__global__ __launch_bounds__(256) void sweep_kernel(
    const uint32* __restrict__ pk,
    const float* __restrict__ yin, float* __restrict__ yout,
    const float* __restrict__ x,
    const float* __restrict__ eps_p, const float* __restrict__ k_p,
    const int* __restrict__ nu_p,
    float* __restrict__ out, int n_edges) {
  __shared__ float bsum;
  if (LAST) { if (threadIdx.x == 0) bsum = 0.0f; __syncthreads(); }
  float inv_eps = 1.0f / eps_p[0];
  float kk = k_p[0];
  float a  = 4.0f * inv_eps + 2.0f * (float)nu_p[0] / (kk * kk) + 10.0f;
  float bq = -4.0f * inv_eps * (1.0f / 4096.0f);
  int stride = gridDim.x * BLOCK;
  for (int e = blockIdx.x * BLOCK + threadIdx.x; e < n_edges; e += stride) {
    uint32 p = __builtin_nontemporal_load(pk + e);
    float g = (float)(p & 0xFFFu) * yin[p >> 12];
    #pragma unroll
    for (int off = 16; off > 0; off >>= 1) g += __shfl_down(g, off, 32);
    if ((threadIdx.x & 31) == 0) {
      int node = e >> 5;
      float ynew = a * yin[node] + bq * g;
      if (LAST) atomicAdd(&bsum, x[node] * ynew);
      else yout[node] = ynew;
    }
  }
  if (LAST) { __syncthreads(); if (threadIdx.x == 0) atomicAdd(out, bsum); }
}

extern "C" void kernel_launch(void* const* d_in, const int* in_sizes, int n_in,
                              void* d_out, int out_size, void* d_ws, size_t ws_size,
                              hipStream_t stream) {
  const float* x     = (const float*)d_in[0];
  const int*   nbr   = (const int*)d_in[1];
  const float* dist  = (const float*)d_in[2];
  const float* eps_p = (const float*)d_in[3];
  const float* k_p   = (const float*)d_in[4];
  const int*   nu_p  = (const int*)d_in[5];
  float* out = (float*)d_out;

  int n  = in_sizes[0];   // 1,000,000 nodes  (< 2^20 -> 20-bit index fits)
  int ne = in_sizes[1];   // 32,000,000 edges

  uint32* pk   = (uint32*)d_ws;         // [ne]  packed edges
  __half2* z4  = (__half2*)(pk + ne);   // [n]   (Dinv, x) in f16
  float* y1    = (float*)(z4 + n);      // [n]
  float* y2    = y1 + n;                // [n]

  (void)hipMemsetAsync(d_out, 0, sizeof(float), stream);

  // co-resident grid size (query once; 256 CUs on MI355X)
  static int grid_co = 0;
  if (grid_co == 0) {
    int nb = 0;
    if (hipOccupancyMaxActiveBlocksPerMultiprocessor(&nb, mega_kernel, BLOCK, 0)
            != hipSuccess || nb < 1)
      nb = 4;
    grid_co = nb * 256;
  }

  void* args[] = {(void*)&x, (void*)&nbr, (void*)&dist, (void*)&eps_p,
                  (void*)&k_p, (void*)&nu_p, (void*)&pk, (void*)&z4,
                  (void*)&y1, (void*)&y2, (void*)&out, (void*)&ne};
  hipError_t cerr = hipLaunchCooperativeKernel(
      mega_kernel, dim3(grid_co), dim3(BLOCK), args, 0, stream);

  if (cerr != hipSuccess) {
    // proven 4-kernel fallback (R1 structure, 891us)
    int gridE = (ne + BLOCK - 1) / BLOCK;
    int grid4 = (ne + BLOCK * 4 - 1) / (BLOCK * 4);
    dinv_kernel<<<grid4, BLOCK, 0, stream>>>(dist, x, eps_p, z4, ne);
    fsweep_kernel<<<gridE, BLOCK, 0, stream>>>(dist, nbr, z4, x, eps_p, k_p, nu_p, pk, y1, ne);
    sweep_kernel<false><<<gridE, BLOCK, 0, stream>>>(pk, y1, y2, x, eps_p, k_p, nu_p, out, ne);
    sweep_kernel<true ><<<gridE / 8, BLOCK, 0, stream>>>(pk, y2, nullptr, x, eps_p, k_p, nu_p, out, ne);
  }
}